// Round 1
// baseline (118.626 us; speedup 1.0000x reference)
//
#include <hip/hip_runtime.h>

#define DIM 4096
#define LEAF_LVL 12      // leaves: nodes [4095, 8190]
#define SPLIT_LVL 6      // phase 1 computes h up to and including level 6 (nodes 63..126)
#define P1_ROOT_BASE 63  // first node index at level 6
#define N_SUBTREES 64    // 2^6 subtrees, each with 64 leaves

struct Params {
  float wf, uf, bf;
  float wi, ui, bi;
  float wc, uc, bc;
  float wo, uo, bo;
};

__device__ __forceinline__ float fsig(float z) {
  // sigmoid via fast exp; saturates correctly at +/-inf
  return 1.0f / (1.0f + __expf(-z));
}
__device__ __forceinline__ float ftanh(float z) {
  // tanh(z) = 2*sigmoid(2z) - 1 ; saturates to +/-1 correctly
  return 2.0f / (1.0f + __expf(-2.0f * z)) - 1.0f;
}

__device__ __forceinline__ float leaf_node(float x, const Params& p, float& ct_out) {
  float fsum = fsig(p.wf * x + p.bf);            // h_sum = 0 at leaves
  float it = fsig(p.wi * x + p.bi);
  float gt = ftanh(p.wc * x + p.bc);
  float ct = it * gt + fsum;
  float ot = fsig(p.wo * x + p.bo);
  ct_out = ct;
  return ot * ftanh(ct);
}

__device__ __forceinline__ float inner_node(float x, float hl, float hr,
                                            const Params& p, float& ct_out) {
  float hs = hl + hr;
  float fsum = fsig(p.wf * x + p.uf * hl + p.bf)
             + fsig(p.wf * x + p.uf * hr + p.bf);  // x broadcast to both children
  float it = fsig(p.wi * x + p.ui * hs + p.bi);
  float gt = ftanh(p.wc * x + p.uc * hs + p.bc);
  float ct = it * gt + fsum;
  float ot = fsig(p.wo * x + p.uo * hs + p.bo);
  ct_out = ct;
  return ot * ftanh(ct);
}

// Compile-time-unrolled DFS over a subtree whose root is at tree level LVL.
// All live state is O(depth) registers; no runtime-indexed arrays -> no scratch.
template <int LVL>
__device__ __forceinline__ float subtree_h(const float* __restrict__ tv, int node,
                                           int d, const Params& p) {
  if constexpr (LVL == LEAF_LVL) {
    float x = tv[(size_t)node * DIM + d];
    float ct;
    return leaf_node(x, p, ct);
  } else {
    float hl = subtree_h<LVL + 1>(tv, 2 * node + 1, d, p);
    float hr = subtree_h<LVL + 1>(tv, 2 * node + 2, d, p);
    float x = tv[(size_t)node * DIM + d];
    float ct;
    return inner_node(x, hl, hr, p, ct);
  }
}

__device__ __forceinline__ Params load_params(
    int d,
    const float* wf, const float* uf, const float* bf,
    const float* wi, const float* ui, const float* bi,
    const float* wc, const float* uc, const float* bc,
    const float* wo, const float* uo, const float* bo) {
  Params p;
  p.wf = wf[d]; p.uf = uf[d]; p.bf = bf[d];
  p.wi = wi[d]; p.ui = ui[d]; p.bi = bi[d];
  p.wc = wc[d]; p.uc = uc[d]; p.bc = bc[d];
  p.wo = wo[d]; p.uo = uo[d]; p.bo = bo[d];
  return p;
}

// Phase 1: 1024 blocks x 256 threads.
// block = (subtree g in [0,64)) x (channel-block cb in [0,16)); thread owns channel d.
// Reduces tree levels 12..6 in registers; writes h(level-6 node) to ws[g*DIM + d].
__global__ __launch_bounds__(256) void treelstm_p1(
    const float* __restrict__ tv,
    const float* __restrict__ wf, const float* __restrict__ uf, const float* __restrict__ bf,
    const float* __restrict__ wi, const float* __restrict__ ui, const float* __restrict__ bi,
    const float* __restrict__ wc, const float* __restrict__ uc, const float* __restrict__ bc,
    const float* __restrict__ wo, const float* __restrict__ uo, const float* __restrict__ bo,
    float* __restrict__ ws) {
  const int cb = blockIdx.x & 15;          // channel block (adjacent blocks share rows -> L2)
  const int g  = blockIdx.x >> 4;          // subtree index 0..63
  const int d  = cb * 256 + threadIdx.x;   // channel

  const Params p = load_params(d, wf, uf, bf, wi, ui, bi, wc, uc, bc, wo, uo, bo);

  const int root = P1_ROOT_BASE + g;       // level-6 node
  float h = subtree_h<SPLIT_LVL>(tv, root, d, p);
  ws[(size_t)g * DIM + d] = h;
}

// Top-of-tree DFS: leaves of this phase are the staged level-6 h values.
template <int LVL>
__device__ __forceinline__ float top_h(const float* __restrict__ tv,
                                       const float* __restrict__ ws, int node, int d,
                                       const Params& p, float& ct_out) {
  if constexpr (LVL == SPLIT_LVL) {
    ct_out = 0.0f;  // never consumed at this level
    return ws[(size_t)(node - P1_ROOT_BASE) * DIM + d];
  } else {
    float ct_l, ct_r;
    float hl = top_h<LVL + 1>(tv, ws, 2 * node + 1, d, p, ct_l);
    float hr = top_h<LVL + 1>(tv, ws, 2 * node + 2, d, p, ct_r);
    float x = tv[(size_t)node * DIM + d];
    return inner_node(x, hl, hr, p, ct_out);
  }
}

// Phase 2: 64 blocks x 64 threads = 4096 threads (one per channel).
// Reduces levels 5..0; writes root h to out[0..DIM), root c to out[DIM..2*DIM).
__global__ __launch_bounds__(64) void treelstm_p2(
    const float* __restrict__ tv,
    const float* __restrict__ wf, const float* __restrict__ uf, const float* __restrict__ bf,
    const float* __restrict__ wi, const float* __restrict__ ui, const float* __restrict__ bi,
    const float* __restrict__ wc, const float* __restrict__ uc, const float* __restrict__ bc,
    const float* __restrict__ wo, const float* __restrict__ uo, const float* __restrict__ bo,
    const float* __restrict__ ws, float* __restrict__ out) {
  const int d = blockIdx.x * 64 + threadIdx.x;

  const Params p = load_params(d, wf, uf, bf, wi, ui, bi, wc, uc, bc, wo, uo, bo);

  float ct;
  float h = top_h<0>(tv, ws, 0, d, p, ct);
  out[d] = h;
  out[DIM + d] = ct;
}

extern "C" void kernel_launch(void* const* d_in, const int* in_sizes, int n_in,
                              void* d_out, int out_size, void* d_ws, size_t ws_size,
                              hipStream_t stream) {
  const float* tv = (const float*)d_in[0];
  // d_in[1] = depth (int, 13) -- structure hard-coded to depth 13.
  const float* wf = (const float*)d_in[2];
  const float* uf = (const float*)d_in[3];
  const float* bf = (const float*)d_in[4];
  const float* wi = (const float*)d_in[5];
  const float* ui = (const float*)d_in[6];
  const float* bi = (const float*)d_in[7];
  const float* wc = (const float*)d_in[8];
  const float* uc = (const float*)d_in[9];
  const float* bc = (const float*)d_in[10];
  const float* wo = (const float*)d_in[11];
  const float* uo = (const float*)d_in[12];
  const float* bo = (const float*)d_in[13];

  float* ws = (float*)d_ws;           // needs 64 * 4096 * 4 B = 1 MiB
  float* out = (float*)d_out;         // 8192 floats: h then c

  treelstm_p1<<<dim3(N_SUBTREES * 16), dim3(256), 0, stream>>>(
      tv, wf, uf, bf, wi, ui, bi, wc, uc, bc, wo, uo, bo, ws);

  treelstm_p2<<<dim3(64), dim3(64), 0, stream>>>(
      tv, wf, uf, bf, wi, ui, bi, wc, uc, bc, wo, uo, bo, ws, out);
}

// Round 2
// 59.500 us; speedup vs baseline: 1.9937x; 1.9937x over previous
//
#include <hip/hip_runtime.h>

#define DIM 4096
#define LEAF_LVL 12      // leaves: nodes [4095, 8190]

constexpr float LOG2E = 1.44269504088896340736f;
constexpr float TWO_LOG2E = 2.0f * LOG2E;

struct Params {
  float wf, uf, bf;   // pre-scaled by log2e
  float wi, ui, bi;   // pre-scaled by log2e
  float wc, uc, bc;   // pre-scaled by 2*log2e  (tanh = 2*sigmoid(2z)-1)
  float wo, uo, bo;   // pre-scaled by log2e
};

// u is already z*log2e: sigmoid(z) = 1/(1+2^-u). exp2's neg is a free input modifier.
__device__ __forceinline__ float sig2(float u) {
  float e = __builtin_amdgcn_exp2f(-u);
  return __builtin_amdgcn_rcpf(1.0f + e);
}
// u is already 2z*log2e: tanh(z) = 2*sigmoid(2z)-1
__device__ __forceinline__ float tanh2(float u) {
  return fmaf(2.0f, sig2(u), -1.0f);
}

__device__ __forceinline__ float leaf_node(float x, const Params& p) {
  float fsum = sig2(fmaf(p.wf, x, p.bf));           // h_sum = 0 at leaves
  float it = sig2(fmaf(p.wi, x, p.bi));
  float gt = tanh2(fmaf(p.wc, x, p.bc));
  float ct = fmaf(it, gt, fsum);
  float ot = sig2(fmaf(p.wo, x, p.bo));
  return ot * tanh2(ct * TWO_LOG2E);
}

__device__ __forceinline__ float inner_node(float x, float hl, float hr,
                                            const Params& p, float& ct_out) {
  float hs = hl + hr;
  float af = fmaf(p.wf, x, p.bf);
  float fl = sig2(fmaf(p.uf, hl, af));
  float fr = sig2(fmaf(p.uf, hr, af));
  float it = sig2(fmaf(p.ui, hs, fmaf(p.wi, x, p.bi)));
  float gt = tanh2(fmaf(p.uc, hs, fmaf(p.wc, x, p.bc)));
  float ot = sig2(fmaf(p.uo, hs, fmaf(p.wo, x, p.bo)));
  float ct = fmaf(it, gt, fl + fr);
  ct_out = ct;
  return ot * tanh2(ct * TWO_LOG2E);
}

// Compile-time-unrolled DFS; all state in registers (no runtime-indexed arrays).
template <int LVL>
__device__ __forceinline__ float subtree_h(const float* __restrict__ tv, int node,
                                           int d, const Params& p) {
  if constexpr (LVL == LEAF_LVL) {
    float x = tv[(size_t)node * DIM + d];
    return leaf_node(x, p);
  } else {
    float hl = subtree_h<LVL + 1>(tv, 2 * node + 1, d, p);
    float hr = subtree_h<LVL + 1>(tv, 2 * node + 2, d, p);
    float x = tv[(size_t)node * DIM + d];
    float ct;
    return inner_node(x, hl, hr, p, ct);
  }
}

__device__ __forceinline__ Params load_params(
    int d,
    const float* wf, const float* uf, const float* bf,
    const float* wi, const float* ui, const float* bi,
    const float* wc, const float* uc, const float* bc,
    const float* wo, const float* uo, const float* bo) {
  Params p;
  p.wf = wf[d] * LOG2E;     p.uf = uf[d] * LOG2E;     p.bf = bf[d] * LOG2E;
  p.wi = wi[d] * LOG2E;     p.ui = ui[d] * LOG2E;     p.bi = bi[d] * LOG2E;
  p.wc = wc[d] * TWO_LOG2E; p.uc = uc[d] * TWO_LOG2E; p.bc = bc[d] * TWO_LOG2E;
  p.wo = wo[d] * LOG2E;     p.uo = uo[d] * LOG2E;     p.bo = bo[d] * LOG2E;
  return p;
}

// Phase 1: (2^SPLIT subtrees) x (16 channel-blocks) blocks of 256 threads.
// Reduces levels 12..SPLIT in registers; writes h(level-SPLIT node) to ws.
template <int SPLIT>
__global__ __launch_bounds__(256) void treelstm_p1(
    const float* __restrict__ tv,
    const float* __restrict__ wf, const float* __restrict__ uf, const float* __restrict__ bf,
    const float* __restrict__ wi, const float* __restrict__ ui, const float* __restrict__ bi,
    const float* __restrict__ wc, const float* __restrict__ uc, const float* __restrict__ bc,
    const float* __restrict__ wo, const float* __restrict__ uo, const float* __restrict__ bo,
    float* __restrict__ ws) {
  const int cb = blockIdx.x & 15;          // channel block
  const int g  = blockIdx.x >> 4;          // subtree index
  const int d  = cb * 256 + threadIdx.x;   // channel

  const Params p = load_params(d, wf, uf, bf, wi, ui, bi, wc, uc, bc, wo, uo, bo);

  const int root = ((1 << SPLIT) - 1) + g; // level-SPLIT node
  float h = subtree_h<SPLIT>(tv, root, d, p);
  ws[(size_t)g * DIM + d] = h;
}

// Top-of-tree DFS: leaves of this phase are the staged level-SPLIT h values.
template <int SPLIT, int LVL>
__device__ __forceinline__ float top_h(const float* __restrict__ tv,
                                       const float* __restrict__ ws, int node, int d,
                                       const Params& p, float& ct_out) {
  if constexpr (LVL == SPLIT) {
    ct_out = 0.0f;  // never consumed at this level
    return ws[(size_t)(node - ((1 << SPLIT) - 1)) * DIM + d];
  } else {
    float ct_l, ct_r;
    float hl = top_h<SPLIT, LVL + 1>(tv, ws, 2 * node + 1, d, p, ct_l);
    float hr = top_h<SPLIT, LVL + 1>(tv, ws, 2 * node + 2, d, p, ct_r);
    float x = tv[(size_t)node * DIM + d];
    return inner_node(x, hl, hr, p, ct_out);
  }
}

// Phase 2: 16 blocks x 256 threads = 4096 threads (one per channel).
// Reduces levels SPLIT-1..0; writes root h to out[0..DIM), root c to out[DIM..2*DIM).
template <int SPLIT>
__global__ __launch_bounds__(256) void treelstm_p2(
    const float* __restrict__ tv,
    const float* __restrict__ wf, const float* __restrict__ uf, const float* __restrict__ bf,
    const float* __restrict__ wi, const float* __restrict__ ui, const float* __restrict__ bi,
    const float* __restrict__ wc, const float* __restrict__ uc, const float* __restrict__ bc,
    const float* __restrict__ wo, const float* __restrict__ uo, const float* __restrict__ bo,
    const float* __restrict__ ws, float* __restrict__ out) {
  const int d = blockIdx.x * 256 + threadIdx.x;

  const Params p = load_params(d, wf, uf, bf, wi, ui, bi, wc, uc, bc, wo, uo, bo);

  float ct;
  float h = top_h<SPLIT, 0>(tv, ws, 0, d, p, ct);
  out[d] = h;
  out[DIM + d] = ct;
}

extern "C" void kernel_launch(void* const* d_in, const int* in_sizes, int n_in,
                              void* d_out, int out_size, void* d_ws, size_t ws_size,
                              hipStream_t stream) {
  const float* tv = (const float*)d_in[0];
  // d_in[1] = depth (int, 13) -- structure hard-coded to depth 13.
  const float* wf = (const float*)d_in[2];
  const float* uf = (const float*)d_in[3];
  const float* bf = (const float*)d_in[4];
  const float* wi = (const float*)d_in[5];
  const float* ui = (const float*)d_in[6];
  const float* bi = (const float*)d_in[7];
  const float* wc = (const float*)d_in[8];
  const float* uc = (const float*)d_in[9];
  const float* bc = (const float*)d_in[10];
  const float* wo = (const float*)d_in[11];
  const float* uo = (const float*)d_in[12];
  const float* bo = (const float*)d_in[13];

  float* ws = (float*)d_ws;
  float* out = (float*)d_out;   // 8192 floats: h then c

  // Split at level 7 (128 subtrees -> 8192 waves, 100% wave capacity) if the
  // 2 MiB of scratch fits; otherwise the proven level-6 split (1 MiB).
  const size_t need7 = (size_t)128 * DIM * sizeof(float);
  if (ws_size >= need7) {
    treelstm_p1<7><<<dim3(128 * 16), dim3(256), 0, stream>>>(
        tv, wf, uf, bf, wi, ui, bi, wc, uc, bc, wo, uo, bo, ws);
    treelstm_p2<7><<<dim3(16), dim3(256), 0, stream>>>(
        tv, wf, uf, bf, wi, ui, bi, wc, uc, bc, wo, uo, bo, ws, out);
  } else {
    treelstm_p1<6><<<dim3(64 * 16), dim3(256), 0, stream>>>(
        tv, wf, uf, bf, wi, ui, bi, wc, uc, bc, wo, uo, bo, ws);
    treelstm_p2<6><<<dim3(16), dim3(256), 0, stream>>>(
        tv, wf, uf, bf, wi, ui, bi, wc, uc, bc, wo, uo, bo, ws, out);
  }
}